// Round 1
// 311.632 us; speedup vs baseline: 1.0321x; 1.0321x over previous
//
#include <hip/hip_runtime.h>
#include <hip/hip_bf16.h>
#include <hip/hip_fp16.h>

// GCN 3-layer. R11: agg_kernel restructured for fat gather requests. Theory:
// agg was bound by per-CU outstanding-request queue x latency (VALUBusy 33%,
// all BW ceilings <30%). Old: 1 edge per global_load_dword (256B/request).
// New: 16 lanes x dwordx4 per edge -> 4 edges (F=128) / 8 edges (F=64) per
// 1KB request; per-slot fp32 partials reduced once per node via shfl_xor.
// ep loaded per-lane (16 lanes share addr -> broadcast) with one-batch-ahead
// prefetch. CSR build + MFMA gemms + fused val/wt passes unchanged from R10.

#define K_IN 128              // all layers have in_features == 128
#define FIX_SCALE 8388608.0f  // 2^23 fixed point for ew sums
#define CE 4096               // edges per partition block (1024 thr x 4)

typedef _Float16 f16x8 __attribute__((ext_vector_type(8)));
typedef float f32x4 __attribute__((ext_vector_type(4)));

// ---------- pass 1: per-block bucket histogram + local rank (+W prep tail) ----------
__global__ __launch_bounds__(1024) void part_count_wt(
    const int* __restrict__ dst, int* __restrict__ counts,
    unsigned short* __restrict__ lrank, int nb, int nblk, int e,
    const float* __restrict__ W1, const float* __restrict__ W2,
    const float* __restrict__ W3, _Float16* __restrict__ Wt1,
    _Float16* __restrict__ Wt2, _Float16* __restrict__ Wt3) {
    int blk = blockIdx.x;
    if (blk >= nblk) {  // tail blocks: Wt[n][k] fp16 = W[k][n] fp32
        int i = (blk - nblk) * 1024 + threadIdx.x;
        if (i < 128 * 128) {
            int k = i >> 7, nn = i & 127;
            Wt1[(size_t)nn * 128 + k] = (_Float16)W1[i];
        } else if (i < 2 * 128 * 128) {
            int j = i - 128 * 128, k = j >> 7, nn = j & 127;
            Wt2[(size_t)nn * 128 + k] = (_Float16)W2[j];
        } else if (i < 2 * 128 * 128 + 64 * 128) {
            int l = i - 2 * 128 * 128, k = l >> 6, nn = l & 63;
            Wt3[(size_t)nn * 128 + k] = (_Float16)W3[l];
        }
        return;
    }
    __shared__ int c[256];  // nb <= 256
    int t = threadIdx.x;
    for (int i = t; i < nb; i += 1024) c[i] = 0;
    __syncthreads();
    int b0 = blk * CE;
#pragma unroll
    for (int j = 0; j < 4; j++) {
        int i = b0 + j * 1024 + t;
        if (i < e) {
            int b = dst[i] >> 8;
            int r = atomicAdd(&c[b], 1);  // LDS atomic
            lrank[i] = (unsigned short)r;
        }
    }
    __syncthreads();
    for (int i = t; i < nb; i += 1024) counts[(size_t)i * nblk + blk] = c[i];
}

// ---------- pass 2: parallel exclusive scan over counts[nb*nblk] ----------
__global__ __launch_bounds__(256) void reduce_kernel(const int* __restrict__ v,
                                                     int* __restrict__ bs, int m) {
    __shared__ int s[256];
    int t = threadIdx.x, i = blockIdx.x * 256 + t;
    s[t] = (i < m) ? v[i] : 0;
    __syncthreads();
    for (int off = 128; off > 0; off >>= 1) {
        if (t < off) s[t] += s[t + off];
        __syncthreads();
    }
    if (t == 0) bs[blockIdx.x] = s[0];
}

__global__ __launch_bounds__(1024) void scanb1024(const int* __restrict__ bs,
                                                  int* __restrict__ bo, int nbb) {
    __shared__ int s[1024];
    int t = threadIdx.x;
    s[t] = (t < nbb) ? bs[t] : 0;
    __syncthreads();
    for (int off = 1; off < 1024; off <<= 1) {
        int cur = s[t];
        int add = (t >= off) ? s[t - off] : 0;
        __syncthreads();
        s[t] = cur + add;
        __syncthreads();
    }
    if (t < nbb) bo[t] = (t == 0) ? 0 : s[t - 1];
}

__global__ __launch_bounds__(256) void scanw_kernel(const int* __restrict__ v,
                                                    const int* __restrict__ bo,
                                                    int* __restrict__ outp, int m) {
    __shared__ int s[256];
    int t = threadIdx.x, i = blockIdx.x * 256 + t;
    int c = (i < m) ? v[i] : 0;
    s[t] = c;
    __syncthreads();
    for (int off = 1; off < 256; off <<= 1) {
        int cur = s[t];
        int add = (t >= off) ? s[t - off] : 0;
        __syncthreads();
        s[t] = cur + add;
        __syncthreads();
    }
    if (i < m) outp[i] = bo[blockIdx.x] + (s[t] - c);  // exclusive
}

// ---------- pass 3: scatter into bucket-sorted order (packed src|dlow) ----------
__global__ __launch_bounds__(1024) void part_scatter(const int* __restrict__ src,
                                                     const int* __restrict__ dst,
                                                     const float* __restrict__ ew,
                                                     const int* __restrict__ base,
                                                     const unsigned short* __restrict__ lrank,
                                                     int2* __restrict__ arr1,
                                                     int nblk, int e) {
    int t = threadIdx.x, blk = blockIdx.x;
    int b0 = blk * CE;
#pragma unroll
    for (int j = 0; j < 4; j++) {
        int i = b0 + j * 1024 + t;
        if (i < e) {
            int d = dst[i];
            int b = d >> 8;
            int pos = base[(size_t)b * nblk + blk] + lrank[i];
            arr1[pos] = make_int2((src[i] << 8) | (d & 255), __float_as_int(ew[i]));
        }
    }
}

// ---------- pass 4: per-bucket CSR finalize (one 64-bit LDS atomic/edge) ----------
__global__ __launch_bounds__(1024) void bucket_csr(const int2* __restrict__ arr1,
                                                   const int* __restrict__ base,
                                                   unsigned short* __restrict__ rank2,
                                                   float* __restrict__ dinv,
                                                   int* __restrict__ row_ptr,
                                                   int2* __restrict__ ep,
                                                   int nb, int nblk, int n, int e) {
    __shared__ unsigned long long pk[256];  // cnt lo32 | fx-sum hi32
    __shared__ int nbase[256];
    __shared__ float ldsdinv[256];
    __shared__ int ss[256];
    int t = threadIdx.x, b = blockIdx.x;
    int beg = base[(size_t)b * nblk];
    int end = (b + 1 < nb) ? base[(size_t)(b + 1) * nblk] : e;
    if (t < 256) pk[t] = 0ULL;
    __syncthreads();
    for (int i = beg + t; i < end; i += 1024) {
        int2 a = arr1[i];
        int ld = a.x & 255;
        float w = __int_as_float(a.y);
        unsigned long long fx = (unsigned long long)(unsigned int)(w * FIX_SCALE + 0.5f);
        unsigned long long old = atomicAdd(&pk[ld], (fx << 32) | 1ULL);  // LDS, deterministic
        rank2[i] = (unsigned short)(old & 0xffffffffULL);
    }
    __syncthreads();
    int cnt = (t < 256) ? (int)(pk[t] & 0xffffffffULL) : 0;
    if (t < 256) ss[t] = cnt;
    __syncthreads();
    for (int off = 1; off < 256; off <<= 1) {
        int cur = 0, add = 0;
        if (t < 256) { cur = ss[t]; add = (t >= off) ? ss[t - off] : 0; }
        __syncthreads();
        if (t < 256) ss[t] = cur + add;
        __syncthreads();
    }
    if (t < 256) {
        nbase[t] = ss[t] - cnt;
        int d = b * 256 + t;
        if (d < n) {
            float dv = rsqrtf(1.0f + (float)(unsigned int)(pk[t] >> 32) * (1.0f / FIX_SCALE));
            dinv[d] = dv;
            ldsdinv[t] = dv;
            row_ptr[d] = beg + nbase[t];
        }
    }
    __syncthreads();
    for (int i = beg + t; i < end; i += 1024) {
        int2 a = arr1[i];
        int ld = a.x & 255;
        int pos = beg + nbase[ld] + rank2[i];
        float w = __int_as_float(a.y) * ldsdinv[ld];
        ep[pos] = make_int2(a.x >> 8, __float_as_int(w));  // src index, w*dinv[dst]
    }
}

// ---------- MFMA GEMM (+optional fused val pass in tail blocks) ----------
// H[n x NOUT](fp16) = X[n x 128] @ W. val: ep -> (src*256 byte off, w*dinv[src]).
template <int NOUT, bool XF16, bool FUSEVAL>
__global__ __launch_bounds__(256) void mfma_gemm(const void* __restrict__ Xv,
                                                 const _Float16* __restrict__ Wt,
                                                 _Float16* __restrict__ H, int n,
                                                 int gGemm, int vblk,
                                                 int2* __restrict__ ep,
                                                 const float* __restrict__ dinv,
                                                 int* __restrict__ row_ptr, int e) {
    constexpr int CTW = NOUT / 64;  // col-tiles per wave: 2 (NOUT=128) / 1 (64)
    __shared__ _Float16 Xs[64][136];   // +8 pad: row stride 272B -> 2-way banks
    __shared__ _Float16 Ws[NOUT][136];
    int t = threadIdx.x;
    if (FUSEVAL && (int)blockIdx.x >= gGemm) {  // tail blocks: val pass
        int vb = blockIdx.x - gGemm;
        if (vb == 0 && t == 0) row_ptr[n] = e;
        for (int i = vb * 256 + t; i < e; i += vblk * 256) {
            int2 a = ep[i];
            float w = __int_as_float(a.y) * dinv[a.x];
            ep[i] = make_int2(a.x << 8, __float_as_int(w));  // byte off (fp16 row F=128)
        }
        return;
    }
    int row0 = blockIdx.x * 64;

    for (int i = t * 8; i < NOUT * K_IN; i += 2048) {
        int nn = i >> 7, k = i & 127;
        *(uint4*)&Ws[nn][k] = *(const uint4*)&Wt[i];
    }
    if (XF16) {
        const _Float16* X = (const _Float16*)Xv;
        for (int i = t * 8; i < 64 * K_IN; i += 2048) {
            int r = i >> 7, k = i & 127;
            int row = row0 + r;
            uint4 v = make_uint4(0u, 0u, 0u, 0u);
            if (row < n) v = *(const uint4*)(X + (size_t)row * K_IN + k);
            *(uint4*)&Xs[r][k] = v;
        }
    } else {
        const float* X = (const float*)Xv;
        for (int i = t * 4; i < 64 * K_IN; i += 1024) {
            int r = i >> 7, k = i & 127;
            int row = row0 + r;
            float4 x4 = make_float4(0.f, 0.f, 0.f, 0.f);
            if (row < n) x4 = *(const float4*)(X + (size_t)row * K_IN + k);
            union { _Float16 h[4]; uint2 u; } uu;
            uu.h[0] = (_Float16)x4.x; uu.h[1] = (_Float16)x4.y;
            uu.h[2] = (_Float16)x4.z; uu.h[3] = (_Float16)x4.w;
            *(uint2*)&Xs[r][k] = uu.u;
        }
    }
    __syncthreads();

    int lane = t & 63, w = t >> 6;
    int m = lane & 15, g = lane >> 4;
    f32x4 acc[4][CTW];
#pragma unroll
    for (int mt = 0; mt < 4; mt++)
#pragma unroll
        for (int ct = 0; ct < CTW; ct++) acc[mt][ct] = (f32x4){0.f, 0.f, 0.f, 0.f};

#pragma unroll
    for (int kt = 0; kt < 4; kt++) {
        int kb = kt * 32 + g * 8;
        f16x8 a[4];
#pragma unroll
        for (int mt = 0; mt < 4; mt++) a[mt] = *(const f16x8*)&Xs[mt * 16 + m][kb];
#pragma unroll
        for (int ct = 0; ct < CTW; ct++) {
            int nn = w * (16 * CTW) + ct * 16 + m;
            f16x8 b = *(const f16x8*)&Ws[nn][kb];
#pragma unroll
            for (int mt = 0; mt < 4; mt++)
                acc[mt][ct] = __builtin_amdgcn_mfma_f32_16x16x32_f16(a[mt], b, acc[mt][ct], 0, 0, 0);
        }
    }

#pragma unroll
    for (int mt = 0; mt < 4; mt++) {
#pragma unroll
        for (int r = 0; r < 4; r++) {
            int row = row0 + mt * 16 + g * 4 + r;
            if (row < n) {
#pragma unroll
                for (int ct = 0; ct < CTW; ct++)
                    H[(size_t)row * NOUT + w * (16 * CTW) + ct * 16 + m] =
                        (_Float16)acc[mt][ct][r];
            }
        }
    }
}

// ---------- aggregation: fat gathers. 16 lanes x dwordx4 per edge ----------
// F=128: 4 edges/instruction (1KB request). F=64: 8 edges/instruction.
// Per-lane fp32 partials per edge-slot; one shfl_xor tree per node at the end.
template <int F, bool RELU, bool OF16>
__global__ __launch_bounds__(256) void agg_kernel(const __half* __restrict__ H,
                                                  const int* __restrict__ row_ptr,
                                                  const int2* __restrict__ ep,
                                                  const float* __restrict__ dinv,
                                                  const float* __restrict__ bias,
                                                  void* __restrict__ outv, int n) {
    constexpr int LPE = (F == 128) ? 16 : 8;  // lanes per edge (16B each)
    constexpr int EPW = 64 / LPE;             // edges per gather instruction
    constexpr int UNC = (F == 128) ? 4 : 2;   // chunks in flight
    int wid = threadIdx.x >> 6;
    int lane = threadIdx.x & 63;
    int node = blockIdx.x * 4 + wid;
    if (node >= n) return;

    int start = __builtin_amdgcn_readfirstlane(row_ptr[node]);
    int end   = __builtin_amdgcn_readfirstlane(row_ptr[node + 1]);
    float di = dinv[node];
    float sw = di * di;

    int g  = lane / LPE;        // edge slot within chunk (0..EPW-1)
    int fl = lane & (LPE - 1);  // 16-byte feature sub-block
    const unsigned flb = (unsigned)fl * 16u;
    const char* Hb = (const char*)H;

    float acc[8];
    {  // self term: only edge-slot 0 contributes (others add 0)
        uint4 sv = *(const uint4*)(Hb + (size_t)node * (F * 2) + flb);
        const __half2* sh = (const __half2*)&sv;
        float gm = (g == 0) ? sw : 0.0f;
#pragma unroll
        for (int j = 0; j < 4; j++) {
            float2 f = __half22float2(sh[j]);
            acc[2 * j]     = gm * f.x;
            acc[2 * j + 1] = gm * f.y;
        }
    }

    int len = end - start;
    int nch = (len + EPW - 1) / EPW;  // chunks of EPW edges
    int pg  = start + g;              // this lane's slot position

    auto ldep = [&](int c) -> int2 {  // clamped + weight-zeroed ep fetch
        int p = pg + c * EPW;
        int q = (p < end) ? p : (end - 1);
        int2 t = ep[q];
        if (p >= end) t.y = 0;
        return t;
    };

    if (nch > 0) {
        int2 e[UNC];
#pragma unroll
        for (int u = 0; u < UNC; u++) e[u] = ldep(u);
        for (int c0 = 0; c0 < nch; c0 += UNC) {
            uint4 v[UNC];
#pragma unroll
            for (int u = 0; u < UNC; u++) {
                unsigned off = (unsigned)e[u].x;  // src*256 (fp16 row, F=128)
                if (F == 64) off >>= 1;           // src*128
                v[u] = *(const uint4*)(Hb + (off + flb));
            }
            int2 e2[UNC];  // prefetch next batch's ep under the consume phase
#pragma unroll
            for (int u = 0; u < UNC; u++) e2[u] = ldep(c0 + UNC + u);
#pragma unroll
            for (int u = 0; u < UNC; u++) {
                float w = __int_as_float(e[u].y);
                const __half2* h2 = (const __half2*)&v[u];
#pragma unroll
                for (int j = 0; j < 4; j++) {
                    float2 f = __half22float2(h2[j]);
                    acc[2 * j]     = fmaf(w, f.x, acc[2 * j]);
                    acc[2 * j + 1] = fmaf(w, f.y, acc[2 * j + 1]);
                }
            }
#pragma unroll
            for (int u = 0; u < UNC; u++) e[u] = e2[u];
        }
    }

    // cross-slot reduce: lanes {fl, fl+LPE, ...} hold partials of same features
#pragma unroll
    for (int mask = LPE; mask < 64; mask <<= 1) {
#pragma unroll
        for (int j = 0; j < 8; j++) acc[j] += __shfl_xor(acc[j], mask, 64);
    }

    if (g == 0) {  // 16 (or 8) lanes hold the full row; write 16B each
        float4 b0 = *(const float4*)(bias + fl * 8);
        float4 b1 = *(const float4*)(bias + fl * 8 + 4);
        float o[8] = {acc[0] + b0.x, acc[1] + b0.y, acc[2] + b0.z, acc[3] + b0.w,
                      acc[4] + b1.x, acc[5] + b1.y, acc[6] + b1.z, acc[7] + b1.w};
        if (RELU) {
#pragma unroll
            for (int j = 0; j < 8; j++) o[j] = fmaxf(o[j], 0.0f);
        }
        if (OF16) {
            union { __half2 h[4]; uint4 u; } r;
#pragma unroll
            for (int j = 0; j < 4; j++) r.h[j] = __floats2half2_rn(o[2 * j], o[2 * j + 1]);
            *(uint4*)((char*)outv + (size_t)node * (F * 2) + flb) = r.u;
        } else {
            float* op = (float*)outv + (size_t)node * F + fl * 8;
            *(float4*)op       = make_float4(o[0], o[1], o[2], o[3]);
            *(float4*)(op + 4) = make_float4(o[4], o[5], o[6], o[7]);
        }
    }
}

// ---------- launch ----------

extern "C" void kernel_launch(void* const* d_in, const int* in_sizes, int n_in,
                              void* d_out, int out_size, void* d_ws, size_t ws_size,
                              hipStream_t stream) {
    const float* x   = (const float*)d_in[0];
    const int*   ei  = (const int*)d_in[1];   // int32 (JAX x64 disabled)
    const float* ew  = (const float*)d_in[2];
    const float* W1  = (const float*)d_in[3];
    const float* b1  = (const float*)d_in[4];
    const float* W2  = (const float*)d_in[5];
    const float* b2  = (const float*)d_in[6];
    const float* W3  = (const float*)d_in[7];
    const float* b3  = (const float*)d_in[8];
    float* out = (float*)d_out;

    const int N = in_sizes[0] / K_IN;
    const int E = in_sizes[2];
    const int* src = ei;
    const int* dst = ei + E;

    const int NB   = (N + 255) >> 8;     // buckets, <=256
    const int NBLK = (E + CE - 1) / CE;  // partition blocks
    const int M    = NB * NBLK;
    const int NBB  = (M + 255) / 256;
    const int NWT  = (2 * 128 * 128 + 64 * 128 + 1023) / 1024;  // wt_prep tail blocks
    const int VBLK = 1024;                                      // val tail blocks

    char* w = (char*)d_ws;
    auto alloc = [&](size_t bytes) {
        void* p = (void*)w;
        w += (bytes + 255) & ~(size_t)255;
        return p;
    };
    int*            counts = (int*)alloc((size_t)M * 4);
    int*            base   = (int*)alloc((size_t)M * 4);
    int*            bsM    = (int*)alloc((size_t)NBB * 4);
    int*            boM    = (int*)alloc((size_t)NBB * 4);
    unsigned short* lrank  = (unsigned short*)alloc((size_t)E * 2);  // reused as rank2
    int2*           arr1   = (int2*)alloc((size_t)E * 8);
    float*          dinv   = (float*)alloc((size_t)N * 4);
    int*            row_ptr= (int*)alloc((size_t)(N + 1) * 4);
    int2*           ep     = (int2*)alloc((size_t)E * 8);
    _Float16*       Wt1    = (_Float16*)alloc(128 * 128 * 2);
    _Float16*       Wt2    = (_Float16*)alloc(128 * 128 * 2);
    _Float16*       Wt3    = (_Float16*)alloc(64 * 128 * 2);
    _Float16*       bufH   = (_Float16*)alloc((size_t)N * 128 * 2);  // gemm out
    _Float16*       bufX   = (_Float16*)alloc((size_t)N * 128 * 2);  // agg out (fp16)

    int gGemm = (N + 63) / 64;
    int gAgg  = (N + 3) / 4;

    // ---- CSR build (no global atomics) + fused W prep ----
    part_count_wt<<<NBLK + NWT, 1024, 0, stream>>>(dst, counts, lrank, NB, NBLK, E,
                                                   W1, W2, W3, Wt1, Wt2, Wt3);
    reduce_kernel<<<NBB, 256, 0, stream>>>(counts, bsM, M);
    scanb1024<<<1, 1024, 0, stream>>>(bsM, boM, NBB);
    scanw_kernel<<<NBB, 256, 0, stream>>>(counts, boM, base, M);
    part_scatter<<<NBLK, 1024, 0, stream>>>(src, dst, ew, base, lrank, arr1, NBLK, E);
    bucket_csr<<<NB, 1024, 0, stream>>>(arr1, base, lrank, dinv, row_ptr, ep,
                                        NB, NBLK, N, E);

    // ---- layers (gemm1 carries the fused val pass in tail blocks) ----
    mfma_gemm<128, false, true><<<gGemm + VBLK, 256, 0, stream>>>(
        x, Wt1, bufH, N, gGemm, VBLK, ep, dinv, row_ptr, E);
    agg_kernel<128, true, true><<<gAgg, 256, 0, stream>>>((const __half*)bufH, row_ptr, ep,
                                                          dinv, b1, bufX, N);
    mfma_gemm<128, true, false><<<gGemm, 256, 0, stream>>>(
        bufX, Wt2, bufH, N, gGemm, 0, nullptr, nullptr, nullptr, 0);
    agg_kernel<128, true, true><<<gAgg, 256, 0, stream>>>((const __half*)bufH, row_ptr, ep,
                                                          dinv, b2, bufX, N);
    mfma_gemm<64, true, false><<<gGemm, 256, 0, stream>>>(
        bufX, Wt3, bufH, N, gGemm, 0, nullptr, nullptr, nullptr, 0);
    agg_kernel<64, false, false><<<gAgg, 256, 0, stream>>>((const __half*)bufH, row_ptr, ep,
                                                           dinv, b3, out, N);
}